// Round 2
// baseline (315.704 us; speedup 1.0000x reference)
//
#include <hip/hip_runtime.h>
#include <hip/hip_bf16.h>
#include <stdint.h>

#define BATCH   4096
#define T_DIM   1024
#define NSTATE  64
#define NITER   255          // quad (4-step) iterations; + 1 final triple iter = 1023 steps
#define PSTR    72           // padded LDS row stride (bf16 elems): 144B, 16B-aligned

typedef short  bf16x8 __attribute__((ext_vector_type(8)));
typedef float  f32x4  __attribute__((ext_vector_type(4)));

// d_ws layout
#define WS_ATQ    0                       // bf16 ATQ[16][64][64] : ATQ[m][s][i] = Q_m[i][s]
#define WS_ATR    131072                  // bf16 ATR[8][64][64]  : triples, transposed
#define WS_PIE    196608                  // float piE[2][64]   : pi[s]*E[s][o]
#define WS_PIESUM 197120                  // float piEsum[2]    : sum_s pi[s]*E[s][o]

// ---------------------------------------------------------------------------
// Pre-kernel: 16 blocks. Block m builds Q_m = T_{b1}T_{b2}T_{b3}T_{b4}
// (emission-folded, prob space), b1 = m&1 applied FIRST (alpha * Q).
// Blocks with b4==0 also build triple R_{m&7} = T_{b1}T_{b2}T_{b3}.
// Both stored TRANSPOSED bf16. Block 0 builds piE/piEsum and zeroes out.
// ---------------------------------------------------------------------------
__global__ __launch_bounds__(256) void hmm_pre(
    const float* __restrict__ Tmat, const float* __restrict__ Emat,
    const float* __restrict__ Pi, unsigned char* __restrict__ ws,
    float* __restrict__ out)
{
    __shared__ float sT [64][64];
    __shared__ float sT0[64][64];
    __shared__ float sT1[64][64];
    __shared__ float sPA[64][64];
    __shared__ float sPB[64][64];
    __shared__ float sE[2][64];
    const int tid = threadIdx.x;
    const int m   = blockIdx.x;            // 0..15

    if (tid < 64) {                        // row softmax of T, emission softmax
        const int r = tid;
        float mx = -1e30f;
        for (int j = 0; j < 64; j++) mx = fmaxf(mx, Tmat[r*64+j]);
        float z = 0.f;
        for (int j = 0; j < 64; j++) z += __expf(Tmat[r*64+j] - mx);
        const float inv = 1.0f / z;
        for (int j = 0; j < 64; j++) sT[r][j] = __expf(Tmat[r*64+j] - mx) * inv;
        const float e0 = Emat[r*2+0], e1 = Emat[r*2+1];
        const float em = fmaxf(e0, e1);
        const float p0 = __expf(e0-em), p1 = __expf(e1-em);
        const float ez = 1.0f / (p0 + p1);
        sE[0][r] = p0 * ez;  sE[1][r] = p1 * ez;
    }
    __syncthreads();

    for (int k = tid; k < 4096; k += 256) {   // T_y = T * diag(E[:,y])
        const int i = k >> 6, j = k & 63;
        const float t = sT[i][j];
        sT0[i][j] = t * sE[0][j];
        sT1[i][j] = t * sE[1][j];
    }
    __syncthreads();

    const int b1 = m & 1, b2 = (m >> 1) & 1, b3 = (m >> 2) & 1, b4 = (m >> 3) & 1;
    const float (*A1)[64] = b1 ? sT1 : sT0;
    const float (*A2)[64] = b2 ? sT1 : sT0;
    const float (*A3)[64] = b3 ? sT1 : sT0;
    const float (*A4)[64] = b4 ? sT1 : sT0;
    for (int k = tid; k < 4096; k += 256) {   // PA = T_{b1} T_{b2}, PB = T_{b3} T_{b4}
        const int i = k >> 6, j = k & 63;
        float a = 0.f, b = 0.f;
        for (int q = 0; q < 64; q++) { a += A1[i][q] * A2[q][j]; b += A3[i][q] * A4[q][j]; }
        sPA[i][j] = a;  sPB[i][j] = b;
    }
    __syncthreads();

    __hip_bfloat16* ATQ = (__hip_bfloat16*)(ws + WS_ATQ);
    __hip_bfloat16* ATR = (__hip_bfloat16*)(ws + WS_ATR);
    for (int k = tid; k < 4096; k += 256) {   // Q = PA*PB, store transposed
        const int i = k >> 6, j = k & 63;
        float acc = 0.f;
        for (int q = 0; q < 64; q++) acc += sPA[i][q] * sPB[q][j];
        ATQ[(m*64 + j)*64 + i] = __float2bfloat16(acc);
    }
    if (b4 == 0) {                            // R = PA * T_{b3}, store transposed
        for (int k = tid; k < 4096; k += 256) {
            const int i = k >> 6, j = k & 63;
            float acc = 0.f;
            for (int q = 0; q < 64; q++) acc += sPA[i][q] * A3[q][j];
            ATR[((m & 7)*64 + j)*64 + i] = __float2bfloat16(acc);
        }
    }

    if (m == 0 && tid == 0) {                 // piE + piEsum + zero output
        float mx = -1e30f;
        for (int s = 0; s < 64; s++) mx = fmaxf(mx, Pi[s]);
        float z = 0.f;
        for (int s = 0; s < 64; s++) z += __expf(Pi[s] - mx);
        const float inv = 1.0f / z;
        float* piE = (float*)(ws + WS_PIE);
        float* piEsum = (float*)(ws + WS_PIESUM);
        float s0 = 0.f, s1 = 0.f;
        for (int s = 0; s < 64; s++) {
            const float p = __expf(Pi[s] - mx) * inv;
            piE[s]      = p * sE[0][s];
            piE[64 + s] = p * sE[1][s];
            s0 += piE[s];  s1 += piE[64 + s];
        }
        piEsum[0] = s0;  piEsum[1] = s1;
        *out = 0.f;
    }
}

// ---------------------------------------------------------------------------
// Main kernel: 256 wgs x 256 thr (4 waves). wg = 16 batch rows; wave wv =
// state tile [16wv,16wv+16). Per iter (4 steps): 32 MFMAs (16 quad cands x
// 2 K-halves), per-row 4-bit select, DEFERRED renorm (no extra barrier),
// bf16 write-back. y packed in-kernel via ballot (no shuffle needed:
// v_w bit r = y[64w + r + 1]; iter j uses bits 4j..4j+3 of the stream).
// ---------------------------------------------------------------------------
__global__ __launch_bounds__(256, 1) void hmm_main(
    const int* __restrict__ y, const unsigned char* __restrict__ ws,
    float* __restrict__ out)
{
    __shared__ __align__(16) __hip_bfloat16 P[2][16*PSTR];
    __shared__ float part[2][4][16];      // [buf][tile][bcol] column sums
    __shared__ unsigned long long ywords[16][16];  // [word][bcol]
    __shared__ float logsum[16];

    const int tid  = threadIdx.x;
    const int wv   = tid >> 6;
    const int lane = tid & 63;
    const int bcol = lane & 15;        // batch col within block (B/D col)
    const int g    = lane >> 4;        // lane k-group
    const int R0   = blockIdx.x * 16;

    const __hip_bfloat16* ATQ = (const __hip_bfloat16*)(ws + WS_ATQ);
    const __hip_bfloat16* ATR = (const __hip_bfloat16*)(ws + WS_ATR);
    const float* piE    = (const float*)(ws + WS_PIE);
    const float* piEsum = (const float*)(ws + WS_PIESUM);

    // ---- pack y: wave wv handles rows wv*4..wv*4+3 ----
    #pragma unroll
    for (int q = 0; q < 4; q++) {
        const int* yr = y + (size_t)(R0 + wv*4 + q) * T_DIM;
        unsigned long long myw = 0ull, mynxt = 0ull;
        #pragma unroll
        for (int c = 0; c < 16; c++) {
            const unsigned long long bal = __ballot(yr[c*64 + lane] != 0);
            if (lane == c)     myw  = bal;
            if (lane == c - 1) mynxt = bal;
        }
        if (lane < 16)
            ywords[lane][wv*4 + q] = (myw >> 1) | ((mynxt & 1ull) << 63);
    }

    // ---- A-frags: 16 quad matrices x 2 K-halves ----
    bf16x8 Afr[16][2];
    {
        const int s = wv*16 + bcol;
        #pragma unroll
        for (int m = 0; m < 16; m++)
            #pragma unroll
            for (int h = 0; h < 2; h++)
                Afr[m][h] = *(const bf16x8*)(ATQ + ((m*64 + s)*64) + h*32 + g*8);
    }

    // ---- init alpha0 + its column sums ----
    if (tid < 16) {
        const int y0 = y[(size_t)(R0 + tid) * T_DIM];
        part[0][0][tid] = piEsum[y0];
        part[0][1][tid] = 0.f; part[0][2][tid] = 0.f; part[0][3][tid] = 0.f;
    }
    {
        const int b  = tid >> 4;
        const int s4 = (tid & 15) * 4;
        const int y0 = y[(size_t)(R0 + b) * T_DIM];
        const float* pe = piE + y0*64;
        __hip_bfloat16* dst = &P[0][b*PSTR + s4];
        dst[0] = __float2bfloat16(pe[s4+0]);
        dst[1] = __float2bfloat16(pe[s4+1]);
        dst[2] = __float2bfloat16(pe[s4+2]);
        dst[3] = __float2bfloat16(pe[s4+3]);
    }
    __syncthreads();

    unsigned long long yw = 0ull;
    float lacc = 0.f;
    const f32x4 zero = {0.f, 0.f, 0.f, 0.f};

    for (int j = 0; j < NITER; j++) {
        const int cur = j & 1;
        if ((j & 15) == 0) yw = ywords[j >> 4][bcol];
        const int idx = (int)(yw & 15ull);
        yw >>= 4;

        // B-frags + deferred scale inputs
        const __hip_bfloat16* prow = &P[cur][bcol * PSTR];
        const bf16x8 B0 = *(const bf16x8*)(prow + g*8);
        const bf16x8 B1 = *(const bf16x8*)(prow + 32 + g*8);
        const float Sp = part[cur][0][bcol] + part[cur][1][bcol]
                       + part[cur][2][bcol] + part[cur][3][bcol];
        const float r = __builtin_amdgcn_rcpf(Sp);

        // 16 candidates in two batches of 8 (bounds register pressure)
        f32x4 ca[8];
        #pragma unroll
        for (int m = 0; m < 8; m++) ca[m] = __builtin_amdgcn_mfma_f32_16x16x32_bf16(Afr[m][0], B0, zero, 0, 0, 0);
        #pragma unroll
        for (int m = 0; m < 8; m++) ca[m] = __builtin_amdgcn_mfma_f32_16x16x32_bf16(Afr[m][1], B1, ca[m], 0, 0, 0);
        const bool s1 = idx & 1, s2 = idx & 2, s3 = idx & 4, s4b = idx & 8;
        f32x4 t0 = s1 ? ca[1] : ca[0];
        f32x4 t1 = s1 ? ca[3] : ca[2];
        f32x4 t2 = s1 ? ca[5] : ca[4];
        f32x4 t3 = s1 ? ca[7] : ca[6];
        f32x4 u0 = s2 ? t1 : t0;
        f32x4 u1 = s2 ? t3 : t2;
        const f32x4 Rv0 = s3 ? u1 : u0;
        #pragma unroll
        for (int m = 0; m < 8; m++) ca[m] = __builtin_amdgcn_mfma_f32_16x16x32_bf16(Afr[8+m][0], B0, zero, 0, 0, 0);
        #pragma unroll
        for (int m = 0; m < 8; m++) ca[m] = __builtin_amdgcn_mfma_f32_16x16x32_bf16(Afr[8+m][1], B1, ca[m], 0, 0, 0);
        t0 = s1 ? ca[1] : ca[0];
        t1 = s1 ? ca[3] : ca[2];
        t2 = s1 ? ca[5] : ca[4];
        t3 = s1 ? ca[7] : ca[6];
        u0 = s2 ? t1 : t0;
        u1 = s2 ? t3 : t2;
        const f32x4 Rv1 = s3 ? u1 : u0;
        f32x4 D = s4b ? Rv1 : Rv0;

        // deferred renorm: scale by 1/S_prev, accumulate log S_prev
        lacc += __logf(Sp);
        D *= r;

        // new column sums for next iter
        float p = D.x + D.y + D.z + D.w;
        p += __shfl_xor(p, 16);
        p += __shfl_xor(p, 32);
        if (lane < 16) part[cur ^ 1][wv][lane] = p;

        // cvt + write back: lane owns rows s0..s0+3 of P^T column bcol
        {
            const int s0 = wv*16 + g*4;
            union { __hip_bfloat16 h[4]; uint2 u; } pk;
            pk.h[0] = __float2bfloat16(D.x);
            pk.h[1] = __float2bfloat16(D.y);
            pk.h[2] = __float2bfloat16(D.z);
            pk.h[3] = __float2bfloat16(D.w);
            *(uint2*)&P[cur ^ 1][bcol*PSTR + s0] = pk.u;
        }
        __syncthreads();
    }

    // ---- final triple iter (steps 1021..1023), cur = 1 ----
    {
        bf16x8 Tfr[8][2];
        const int s = wv*16 + bcol;
        #pragma unroll
        for (int m = 0; m < 8; m++)
            #pragma unroll
            for (int h = 0; h < 2; h++)
                Tfr[m][h] = *(const bf16x8*)(ATR + ((m*64 + s)*64) + h*32 + g*8);

        const int idx = (int)(yw & 7ull);   // bit0 = first step
        const __hip_bfloat16* prow = &P[1][bcol * PSTR];
        const bf16x8 B0 = *(const bf16x8*)(prow + g*8);
        const bf16x8 B1 = *(const bf16x8*)(prow + 32 + g*8);
        const float Sp = part[1][0][bcol] + part[1][1][bcol]
                       + part[1][2][bcol] + part[1][3][bcol];
        const float r = __builtin_amdgcn_rcpf(Sp);

        f32x4 ca[8];
        #pragma unroll
        for (int m = 0; m < 8; m++) ca[m] = __builtin_amdgcn_mfma_f32_16x16x32_bf16(Tfr[m][0], B0, zero, 0, 0, 0);
        #pragma unroll
        for (int m = 0; m < 8; m++) ca[m] = __builtin_amdgcn_mfma_f32_16x16x32_bf16(Tfr[m][1], B1, ca[m], 0, 0, 0);
        const bool s1 = idx & 1, s2 = idx & 2, s3 = idx & 4;
        const f32x4 t0 = s1 ? ca[1] : ca[0];
        const f32x4 t1 = s1 ? ca[3] : ca[2];
        const f32x4 t2 = s1 ? ca[5] : ca[4];
        const f32x4 t3 = s1 ? ca[7] : ca[6];
        const f32x4 u0 = s2 ? t1 : t0;
        const f32x4 u1 = s2 ? t3 : t2;
        f32x4 D = s3 ? u1 : u0;

        lacc += __logf(Sp);
        D *= r;

        float p = D.x + D.y + D.z + D.w;
        p += __shfl_xor(p, 16);
        p += __shfl_xor(p, 32);
        if (lane < 16) part[0][wv][lane] = p;
        __syncthreads();
    }

    // ---- epilogue: logprob[b] = lacc[b] + ln(S_final) ----
    if (tid < 16) {
        const float Sf = part[0][0][tid] + part[0][1][tid]
                       + part[0][2][tid] + part[0][3][tid];
        logsum[tid] = lacc + __logf(Sf);
    }
    __syncthreads();
    if (tid == 0) {
        float s = 0.f;
        for (int b = 0; b < 16; b++) s += logsum[b];
        atomicAdd(out, s * (1.0f / BATCH));
    }
}

// ---------------------------------------------------------------------------
extern "C" void kernel_launch(void* const* d_in, const int* in_sizes, int n_in,
                              void* d_out, int out_size, void* d_ws, size_t ws_size,
                              hipStream_t stream) {
    const int*   y  = (const int*)  d_in[0];
    const float* T  = (const float*)d_in[1];
    const float* E  = (const float*)d_in[2];
    const float* Pi = (const float*)d_in[3];
    float* out = (float*)d_out;
    unsigned char* ws = (unsigned char*)d_ws;

    hipLaunchKernelGGL(hmm_pre,  dim3(16),       dim3(256), 0, stream, T, E, Pi, ws, out);
    hipLaunchKernelGGL(hmm_main, dim3(BATCH/16), dim3(256), 0, stream, y, ws, out);
}

// Round 3
// 194.415 us; speedup vs baseline: 1.6239x; 1.6239x over previous
//
#include <hip/hip_runtime.h>
#include <hip/hip_bf16.h>
#include <stdint.h>

#define BATCH 4096
#define TLEN  1024
#define NS    64
#define NF_IT 171        // forward triple iters: steps 1..513
#define NB_IT 170        // backward triple iters: steps 514..1023
#define MSTR  72         // element stride of all 64-row LDS matrices (144B, 16B-aligned)
#define PSTR  72

typedef short bf16x8 __attribute__((ext_vector_type(8)));
typedef float f32x4  __attribute__((ext_vector_type(4)));

// ---- LDS layout (bytes). Matrices are [64][MSTR] bf16 = 9216 B each. ----
#define OFF_S0    0        // T0 plain    (S_b[i][j] = T_b[i][j])
#define OFF_S1    9216     // T1 plain
#define OFF_G0    18432    // T0 transposed (G_b[j][i] = T_b[i][j])
#define OFF_G1    27648
#define OFF_RT    18432    // triple transposed storage (aliases G0; G dead by then)
#define OFF_RP    27648    // triple plain storage      (aliases G1)
#define OFF_W     36864    // 4 pair-products W_c[x][y] = (T_b2 T_b3)[y][x], 4*9216
#define OFF_PE    73728    // float pE[2][64]
#define OFF_PIV   74240    // float piv[64]
// persistent region aliases W (W dead after R-phase):
#define OFF_PF    36864    // bf16 Pf[2][16][PSTR]
#define OFF_PB    41472    // bf16 Pb[2][16][PSTR]
#define OFF_YSF   46080    // u64 ysf[11][16]
#define OFF_YSB   47488    // u64 ysb[11][16]
#define OFF_YBALL 48896    // u64 yball[16][16]
#define OFF_PARTF 50944    // float partsF[2][4][16]
#define OFF_PARTB 51456
#define OFF_LACCB 51968    // float laccB[16]
#define SMEM_SZ   74496

#define MFMA(a,b,c) __builtin_amdgcn_mfma_f32_16x16x32_bf16(a,b,c,0,0,0)

// ---------------------------------------------------------------------------
// One fused kernel. 256 wgs x 512 thr (8 waves). Waves 0-3: forward chain
// (state tiles 0..3); waves 4-7: backward chain. Each wg builds the 8
// emission-folded triple-product matrices R_m = T_b1*T_b2*T_b3 in-LDS via
// MFMA (both transposed layout for fwd A-frags and plain for bwd), packs y
// via ballot, then runs 171/170 triple iters with candidate-select.
// ---------------------------------------------------------------------------
__global__ __launch_bounds__(512, 2) void hmm_fused(
    const int* __restrict__ y, const float* __restrict__ Tmat,
    const float* __restrict__ Emat, const float* __restrict__ Pi,
    float* __restrict__ out)
{
    __shared__ __align__(16) unsigned char SM[SMEM_SZ];

    const int tid  = threadIdx.x;
    const int wv   = tid >> 6;          // 0..7
    const int lane = tid & 63;
    const int lr   = lane & 15;         // MFMA row/col lane index
    const int g    = lane >> 4;         // k-group
    const int R0   = blockIdx.x * 16;   // batch block
    const bool is_fwd = (wv < 4);
    const int tile = wv & 3;            // state tile for main loop

    float* pE  = (float*)(SM + OFF_PE);   // [2][64]
    float* piv = (float*)(SM + OFF_PIV);  // [64]
    const f32x4 zero = {0.f, 0.f, 0.f, 0.f};

    // ---- phase 0: emission softmax + pi softmax (wave 0) ----
    if (tid < 64) {
        const float e0 = Emat[tid*2+0], e1 = Emat[tid*2+1];
        const float em = fmaxf(e0, e1);
        const float p0 = __expf(e0-em), p1 = __expf(e1-em);
        const float ez = 1.0f / (p0 + p1);
        pE[tid]      = p0 * ez;
        pE[64 + tid] = p1 * ez;
        float v = Pi[tid];
        float mx = v;
        #pragma unroll
        for (int d = 1; d < 64; d <<= 1) mx = fmaxf(mx, __shfl_xor(mx, d));
        const float e = __expf(v - mx);
        float z = e;
        #pragma unroll
        for (int d = 1; d < 64; d <<= 1) z += __shfl_xor(z, d);
        piv[tid] = e / z;
    }
    __syncthreads();

    // ---- phase 1: row-softmax of T, emission fold, store plain + transposed ----
    {
        const int r = tid >> 3;           // 0..63
        const int p = tid & 7;            // 8 cols each
        const float4 v0 = *(const float4*)(Tmat + r*64 + p*8);
        const float4 v1 = *(const float4*)(Tmat + r*64 + p*8 + 4);
        float mx = fmaxf(fmaxf(fmaxf(v0.x,v0.y),fmaxf(v0.z,v0.w)),
                         fmaxf(fmaxf(v1.x,v1.y),fmaxf(v1.z,v1.w)));
        mx = fmaxf(mx, __shfl_xor(mx,1));
        mx = fmaxf(mx, __shfl_xor(mx,2));
        mx = fmaxf(mx, __shfl_xor(mx,4));
        float e[8];
        e[0]=__expf(v0.x-mx); e[1]=__expf(v0.y-mx); e[2]=__expf(v0.z-mx); e[3]=__expf(v0.w-mx);
        e[4]=__expf(v1.x-mx); e[5]=__expf(v1.y-mx); e[6]=__expf(v1.z-mx); e[7]=__expf(v1.w-mx);
        float z = e[0]+e[1]+e[2]+e[3]+e[4]+e[5]+e[6]+e[7];
        z += __shfl_xor(z,1); z += __shfl_xor(z,2); z += __shfl_xor(z,4);
        const float inv = 1.0f / z;
        __hip_bfloat16* S0 = (__hip_bfloat16*)(SM + OFF_S0);
        __hip_bfloat16* S1 = (__hip_bfloat16*)(SM + OFF_S1);
        __hip_bfloat16* G0 = (__hip_bfloat16*)(SM + OFF_G0);
        __hip_bfloat16* G1 = (__hip_bfloat16*)(SM + OFF_G1);
        #pragma unroll
        for (int k = 0; k < 8; k++) {
            const int j = p*8 + k;
            const float t = e[k] * inv;
            const __hip_bfloat16 h0 = __float2bfloat16(t * pE[j]);
            const __hip_bfloat16 h1 = __float2bfloat16(t * pE[64 + j]);
            S0[r*MSTR + j] = h0;  S1[r*MSTR + j] = h1;
            G0[j*MSTR + r] = h0;  G1[j*MSTR + r] = h1;
        }
    }
    __syncthreads();

    // ---- phase 2: W_c[x][y] = (T_b2*T_b3)[y][x], c=b2*2+b3; 2 waves per W ----
    {
        const int c  = wv & 3;
        const int b2 = c >> 1, b3 = c & 1;
        const __hip_bfloat16* X = (const __hip_bfloat16*)(SM + (b3 ? OFF_G1 : OFF_G0));
        const __hip_bfloat16* V = (const __hip_bfloat16*)(SM + (b2 ? OFF_S1 : OFF_S0));
        __hip_bfloat16* W = (__hip_bfloat16*)(SM + OFF_W) + c*(64*MSTR);
        const int xh = wv >> 2;           // xtiles xh*2 .. xh*2+1
        #pragma unroll
        for (int x2 = 0; x2 < 2; x2++) {
            const int xt = xh*2 + x2;
            const bf16x8 a0 = *(const bf16x8*)(X + (xt*16+lr)*MSTR + g*8);
            const bf16x8 a1 = *(const bf16x8*)(X + (xt*16+lr)*MSTR + 32 + g*8);
            #pragma unroll
            for (int yb = 0; yb < 4; yb++) {
                const bf16x8 b0 = *(const bf16x8*)(V + (yb*16+lr)*MSTR + g*8);
                const bf16x8 b1 = *(const bf16x8*)(V + (yb*16+lr)*MSTR + 32 + g*8);
                f32x4 d = MFMA(a0, b0, zero);
                d = MFMA(a1, b1, d);
                const int ycol = yb*16 + lr, xb = xt*16 + g*4;
                W[(xb+0)*MSTR + ycol] = __float2bfloat16(d.x);
                W[(xb+1)*MSTR + ycol] = __float2bfloat16(d.y);
                W[(xb+2)*MSTR + ycol] = __float2bfloat16(d.z);
                W[(xb+3)*MSTR + ycol] = __float2bfloat16(d.w);
            }
        }
    }
    __syncthreads();

    // ---- phase 3: triples R_m = T_b1 * (T_b2 T_b3); D[s][i] = R[i][s].
    //      Write Rt[s][i]=R[i][s] (fwd layout) and Rp[i][s]=R[i][s] (bwd),
    //      then every wave frag-loads its tile before buffers are reused. ----
    bf16x8 Afr[8][2];
    {
        __hip_bfloat16* Rt = (__hip_bfloat16*)(SM + OFF_RT);
        __hip_bfloat16* Rp = (__hip_bfloat16*)(SM + OFF_RP);
        #pragma unroll
        for (int m = 0; m < 8; m++) {
            const int b1 = m >> 2, c = m & 3;
            const __hip_bfloat16* X = (const __hip_bfloat16*)(SM + OFF_W) + c*(64*MSTR);
            const __hip_bfloat16* V = (const __hip_bfloat16*)(SM + (b1 ? OFF_S1 : OFF_S0));
            #pragma unroll
            for (int tt = 0; tt < 2; tt++) {
                const int t8 = wv + tt*8;        // tile id 0..15
                const int xt = t8 >> 2, yb = t8 & 3;
                const bf16x8 a0 = *(const bf16x8*)(X + (xt*16+lr)*MSTR + g*8);
                const bf16x8 a1 = *(const bf16x8*)(X + (xt*16+lr)*MSTR + 32 + g*8);
                const bf16x8 b0 = *(const bf16x8*)(V + (yb*16+lr)*MSTR + g*8);
                const bf16x8 b1 = *(const bf16x8*)(V + (yb*16+lr)*MSTR + 32 + g*8);
                f32x4 d = MFMA(a0, b0, zero);
                d = MFMA(a1, b1, d);
                const int ycol = yb*16 + lr, xb = xt*16 + g*4;
                Rt[(xb+0)*MSTR + ycol] = __float2bfloat16(d.x);
                Rt[(xb+1)*MSTR + ycol] = __float2bfloat16(d.y);
                Rt[(xb+2)*MSTR + ycol] = __float2bfloat16(d.z);
                Rt[(xb+3)*MSTR + ycol] = __float2bfloat16(d.w);
                union { __hip_bfloat16 h[4]; uint2 u; } pk;
                pk.h[0] = __float2bfloat16(d.x);
                pk.h[1] = __float2bfloat16(d.y);
                pk.h[2] = __float2bfloat16(d.z);
                pk.h[3] = __float2bfloat16(d.w);
                *(uint2*)(Rp + ycol*MSTR + xb) = pk.u;
            }
            __syncthreads();
            {
                const __hip_bfloat16* RA = is_fwd ? Rt : Rp;
                const int s = tile*16 + lr;
                Afr[m][0] = *(const bf16x8*)(RA + s*MSTR + g*8);
                Afr[m][1] = *(const bf16x8*)(RA + s*MSTR + 32 + g*8);
            }
            __syncthreads();
        }
    }

    // ---- phase 4: ballot-pack y; build per-direction nibble streams ----
    unsigned long long* yball = (unsigned long long*)(SM + OFF_YBALL);
    #pragma unroll
    for (int q = 0; q < 2; q++) {
        const int c = wv*2 + q;
        const int* yr = y + (size_t)(R0 + c) * TLEN;
        #pragma unroll
        for (int w = 0; w < 16; w++) {
            const unsigned long long bal = __ballot(yr[w*64 + lane] != 0);
            if (lane == 0) yball[c*16 + w] = bal;
        }
    }
    __syncthreads();
    {
        const int c = tid & 15, slot = tid >> 4;
        unsigned long long* ysf = (unsigned long long*)(SM + OFF_YSF);
        unsigned long long* ysb = (unsigned long long*)(SM + OFF_YSB);
        if (slot < 11) {
            unsigned long long wd = 0ull;
            for (int n = 0; n < 16; n++) {
                const int i = slot*16 + n;
                if (i < NF_IT) {
                    const int t1 = 3*i + 1;
                    const unsigned long long bA = (yball[c*16 + (t1>>6)] >> (t1 & 63)) & 1ull;
                    const unsigned long long bB = (yball[c*16 + ((t1+1)>>6)] >> ((t1+1) & 63)) & 1ull;
                    const unsigned long long bC = (yball[c*16 + ((t1+2)>>6)] >> ((t1+2) & 63)) & 1ull;
                    wd |= ((bA<<2) | (bB<<1) | bC) << (4*n);
                }
            }
            ysf[slot*16 + c] = wd;
        } else if (slot >= 16 && slot < 27) {
            const int s2 = slot - 16;
            unsigned long long wd = 0ull;
            for (int n = 0; n < 16; n++) {
                const int jj = s2*16 + n;
                if (jj < NB_IT) {
                    const int t = 1021 - 3*jj;
                    const unsigned long long bA = (yball[c*16 + (t>>6)] >> (t & 63)) & 1ull;
                    const unsigned long long bB = (yball[c*16 + ((t+1)>>6)] >> ((t+1) & 63)) & 1ull;
                    const unsigned long long bC = (yball[c*16 + ((t+2)>>6)] >> ((t+2) & 63)) & 1ull;
                    wd |= ((bA<<2) | (bB<<1) | bC) << (4*n);
                }
            }
            ysb[s2*16 + c] = wd;
        }
    }
    // ---- phase 5: init alpha0 (fwd) and ones (bwd) + column part-sums ----
    {
        __hip_bfloat16* Pf = (__hip_bfloat16*)(SM + OFF_PF);
        __hip_bfloat16* Pb = (__hip_bfloat16*)(SM + OFF_PB);
        float* paF = (float*)(SM + OFF_PARTF);
        float* paB = (float*)(SM + OFF_PARTB);
        if (tid < 256) {
            const int b = tid >> 4, s4 = (tid & 15) * 4;
            const int y0 = y[(size_t)(R0 + b) * TLEN];
            const float* pe = pE + y0*64;
            union { __hip_bfloat16 h[4]; uint2 u; } pk;
            pk.h[0] = __float2bfloat16(piv[s4+0]*pe[s4+0]);
            pk.h[1] = __float2bfloat16(piv[s4+1]*pe[s4+1]);
            pk.h[2] = __float2bfloat16(piv[s4+2]*pe[s4+2]);
            pk.h[3] = __float2bfloat16(piv[s4+3]*pe[s4+3]);
            *(uint2*)(Pf + b*PSTR + s4) = pk.u;
        } else {
            const int t2 = tid - 256;
            const int b = t2 >> 4, s4 = (t2 & 15) * 4;
            union { __hip_bfloat16 h[4]; uint2 u; } pk;
            pk.h[0] = pk.h[1] = pk.h[2] = pk.h[3] = __float2bfloat16(1.0f);
            *(uint2*)(Pb + b*PSTR + s4) = pk.u;
        }
        if (tid < 64) {
            const int t = tid >> 4, b = tid & 15;
            const int y0 = y[(size_t)(R0 + b) * TLEN];
            const float* pe = pE + y0*64;
            float s = 0.f;
            #pragma unroll
            for (int k = 0; k < 16; k++) s += piv[t*16+k] * pe[t*16+k];
            paF[t*16 + b] = s;
            paB[t*16 + b] = 16.0f;
        }
    }
    __syncthreads();

    // ---- phase 6: main loop. fwd: 171 triple iters; bwd: 170. ----
    float lacc = 0.f;
    unsigned long long yw = 0ull;
    const int bcol = lr;
    __hip_bfloat16* Parr = (__hip_bfloat16*)(SM + (is_fwd ? OFF_PF : OFF_PB));
    float* parts = (float*)(SM + (is_fwd ? OFF_PARTF : OFF_PARTB));
    const unsigned long long* ys =
        (const unsigned long long*)(SM + (is_fwd ? OFF_YSF : OFF_YSB));
    const int nit = is_fwd ? NF_IT : NB_IT;

    for (int j = 0; j < NF_IT; j++) {
        if (j < nit) {
            const int cur = j & 1;
            if ((j & 15) == 0) yw = ys[(j>>4)*16 + bcol];
            const int idx = (int)(yw & 7ull);
            yw >>= 4;

            const __hip_bfloat16* prow = Parr + cur*(16*PSTR) + bcol*PSTR;
            const bf16x8 B0 = *(const bf16x8*)(prow + g*8);
            const bf16x8 B1 = *(const bf16x8*)(prow + 32 + g*8);
            const float* pc = parts + cur*64;
            const float Sp = pc[bcol] + pc[16+bcol] + pc[32+bcol] + pc[48+bcol];
            const float rs = __builtin_amdgcn_rcpf(Sp);
            lacc += __logf(Sp);

            f32x4 ca[8];
            #pragma unroll
            for (int m = 0; m < 8; m++) ca[m] = MFMA(Afr[m][0], B0, zero);
            #pragma unroll
            for (int m = 0; m < 8; m++) ca[m] = MFMA(Afr[m][1], B1, ca[m]);

            const bool s1 = idx & 1, s2 = idx & 2, s3 = idx & 4;
            const f32x4 t0 = s1 ? ca[1] : ca[0];
            const f32x4 t1 = s1 ? ca[3] : ca[2];
            const f32x4 t2 = s1 ? ca[5] : ca[4];
            const f32x4 t3 = s1 ? ca[7] : ca[6];
            const f32x4 u0 = s2 ? t1 : t0;
            const f32x4 u1 = s2 ? t3 : t2;
            f32x4 D = s3 ? u1 : u0;
            D *= rs;

            float p = D.x + D.y + D.z + D.w;
            p += __shfl_xor(p, 16);
            p += __shfl_xor(p, 32);
            if (lane < 16) parts[(cur^1)*64 + tile*16 + lane] = p;

            union { __hip_bfloat16 h[4]; uint2 u; } pk;
            pk.h[0] = __float2bfloat16(D.x);
            pk.h[1] = __float2bfloat16(D.y);
            pk.h[2] = __float2bfloat16(D.z);
            pk.h[3] = __float2bfloat16(D.w);
            *(uint2*)(Parr + (cur^1)*(16*PSTR) + bcol*PSTR + tile*16 + g*4) = pk.u;
        }
        __syncthreads();
    }

    // ---- epilogue: logprob[b] = laccF + laccB + log( alpha_513[b,:] . c_514[b,:] ) ----
    if (wv == 4 && lane < 16) ((float*)(SM + OFF_LACCB))[lane] = lacc;
    __syncthreads();
    if (tid < 16) {
        const __hip_bfloat16* pf = (const __hip_bfloat16*)(SM + OFF_PF) + 16*PSTR + tid*PSTR; // buf 1
        const __hip_bfloat16* pb = (const __hip_bfloat16*)(SM + OFF_PB) + tid*PSTR;           // buf 0
        float dot = 0.f;
        #pragma unroll
        for (int s = 0; s < 64; s++)
            dot += __bfloat162float(pf[s]) * __bfloat162float(pb[s]);
        float lp = lacc + ((float*)(SM + OFF_LACCB))[tid] + __logf(dot);
        lp += __shfl_xor(lp, 1);
        lp += __shfl_xor(lp, 2);
        lp += __shfl_xor(lp, 4);
        lp += __shfl_xor(lp, 8);
        if (tid == 0) atomicAdd(out, lp * (1.0f / BATCH));
    }
}

// ---------------------------------------------------------------------------
extern "C" void kernel_launch(void* const* d_in, const int* in_sizes, int n_in,
                              void* d_out, int out_size, void* d_ws, size_t ws_size,
                              hipStream_t stream) {
    const int*   y  = (const int*)  d_in[0];
    const float* T  = (const float*)d_in[1];
    const float* E  = (const float*)d_in[2];
    const float* Pi = (const float*)d_in[3];
    float* out = (float*)d_out;

    hipMemsetAsync(out, 0, sizeof(float), stream);
    hipLaunchKernelGGL(hmm_fused, dim3(BATCH/16), dim3(512), 0, stream, y, T, E, Pi, out);
}